// Round 6
// baseline (419.963 us; speedup 1.0000x reference)
//
#include <hip/hip_runtime.h>
#include <hip/hip_bf16.h>

// NonLocalBlock B=4,C=256,H=W=64 (N=4096) — round 6.
//  wcvt : weights fp32 -> bf16 once
//  qkv  : 32-token tiles, grid 512 (2 blocks/CU), LDS x-transpose + MFMA
//  attn : BARRIER-FREE flash. Each wave: 32 queries x 1024 keys (j-split x4
//         within block). K/V frags streamed from L2, P transposed in-register
//         via packed shfl_xor(32) (no LDS, no cross-wave traffic). Partials
//         combined once at end (no-max softmax => plain sums).
//  proj : streaming bf16 MFMA + residual
// ws = QT(=ATT) | KT | V | Wbf = 25.7 MiB.

typedef __attribute__((ext_vector_type(4))) short s16x4;
typedef __attribute__((ext_vector_type(8))) short s16x8;
typedef __attribute__((ext_vector_type(4))) unsigned int u32x4;
typedef __attribute__((ext_vector_type(16))) float f32x16;

#define MFMA32(a, b, c) __builtin_amdgcn_mfma_f32_32x32x16_bf16((a), (b), (c), 0, 0, 0)

constexpr int Cc = 256;
constexpr int Nn = 4096;

__device__ inline short f2bf(float f) {
    unsigned int u = __builtin_bit_cast(unsigned int, f);
    u = (u + 0x7fffu + ((u >> 16) & 1u)) >> 16;   // RNE
    return (short)u;
}
__device__ inline unsigned int pk2(float a, float b) {
    return (unsigned int)(unsigned short)f2bf(a)
         | ((unsigned int)(unsigned short)f2bf(b) << 16);
}

// 32x32x16 bf16 MFMA layouts (m74/m101-verified C/D; A/B symmetric k-map):
//   A[m=lane&31][k=(lane>>5)*8+j]   B[k=(lane>>5)*8+j][n=lane&31]
//   C/D: col=lane&31, row=(r&3)+8*(r>>2)+4*(lane>>5)

// ---------------------------------------------------------------- wcvt
__global__ __launch_bounds__(256, 4) void wcvt_kernel(
    const float* __restrict__ wq, const float* __restrict__ wk,
    const float* __restrict__ wv, const float* __restrict__ wp,
    short* __restrict__ W)
{
    const int m = blockIdx.y;
    const float* src = (m == 0) ? wq : (m == 1) ? wk : (m == 2) ? wv : wp;
    const int idx = (blockIdx.x * 256 + threadIdx.x) * 8;
    float4 a = *(const float4*)(src + idx);
    float4 b = *(const float4*)(src + idx + 4);
    s16x8 p = { f2bf(a.x), f2bf(a.y), f2bf(a.z), f2bf(a.w),
                f2bf(b.x), f2bf(b.y), f2bf(b.z), f2bf(b.w) };
    *(s16x8*)(W + m * 65536 + idx) = p;
}

// ---------------------------------------------------------------- qkv
// 32-token tiles, grid (128 nt, 4 b) = 512 blocks -> 2 blocks/CU.
__global__ __launch_bounds__(256, 2) void qkv_kernel(
    const float* __restrict__ x, const short* __restrict__ W,
    const float* __restrict__ bq, const float* __restrict__ bk,
    const float* __restrict__ bv,
    short* __restrict__ QT, short* __restrict__ KT, short* __restrict__ V)
{
    const int nt = blockIdx.x, b = blockIdx.y;
    const int n0 = nt * 32;
    const int t = threadIdx.x, lane = t & 63, wid = t >> 6, h = lane >> 5, l31 = lane & 31;

    __shared__ alignas(16) short xT[32][264];      // x^T tile [n][c] bf16

    const float* xb = x + (size_t)b * Cc * Nn;
    #pragma unroll
    for (int r = 0; r < 8; ++r) {                  // 32n x 256c transpose+cvt
        int idx = r * 256 + t;
        int n = idx & 31, c = (idx >> 5) * 4;
        float f0 = xb[(size_t)(c + 0) * Nn + n0 + n];
        float f1 = xb[(size_t)(c + 1) * Nn + n0 + n];
        float f2 = xb[(size_t)(c + 2) * Nn + n0 + n];
        float f3 = xb[(size_t)(c + 3) * Nn + n0 + n];
        s16x4 p = { f2bf(f0), f2bf(f1), f2bf(f2), f2bf(f3) };
        *(s16x4*)&xT[n][c] = p;
    }
    __syncthreads();

    // ---- Q,K: D[n][o] (A = xT rows, B = W rows)
    #pragma unroll
    for (int mat = 0; mat < 2; ++mat) {
        const short* Wm = W + mat * 65536;
        const float* bias = (mat == 0) ? bq : bk;
        f32x16 acc[2];
        #pragma unroll
        for (int s = 0; s < 2; ++s)
            #pragma unroll
            for (int r = 0; r < 16; ++r) acc[s][r] = 0.f;
        #pragma unroll 4
        for (int kk = 0; kk < 16; ++kk) {
            s16x8 a = *(const s16x8*)&xT[l31][kk*16 + h*8];
            #pragma unroll
            for (int s = 0; s < 2; ++s) {
                int ot = wid*2 + s;
                s16x8 bb = *(const s16x8*)&Wm[(size_t)(ot*32 + l31) * Cc + kk*16 + h*8];
                acc[s] = MFMA32(a, bb, acc[s]);
            }
        }
        short* dst = ((mat == 0) ? QT : KT) + (size_t)b * Nn * Cc;
        #pragma unroll
        for (int s = 0; s < 2; ++s) {
            int o = (wid*2 + s)*32 + l31;
            float bia = bias[o];
            #pragma unroll
            for (int r = 0; r < 16; ++r) {
                int n = (r & 3) + 8*(r >> 2) + 4*h;
                dst[(size_t)(n0 + n) * Cc + o] = f2bf(acc[s][r] + bia);
            }
        }
    }

    // ---- V: D[o][n] (A = W rows, B = xT rows)
    {
        const short* Wm = W + 2 * 65536;
        f32x16 acc[2];
        #pragma unroll
        for (int s = 0; s < 2; ++s)
            #pragma unroll
            for (int r = 0; r < 16; ++r) acc[s][r] = 0.f;
        #pragma unroll 4
        for (int kk = 0; kk < 16; ++kk) {
            s16x8 bx = *(const s16x8*)&xT[l31][kk*16 + h*8];
            #pragma unroll
            for (int s = 0; s < 2; ++s) {
                int ot = wid*2 + s;
                s16x8 aw = *(const s16x8*)&Wm[(size_t)(ot*32 + l31) * Cc + kk*16 + h*8];
                acc[s] = MFMA32(aw, bx, acc[s]);
            }
        }
        short* dst = V + (size_t)b * Cc * Nn;
        #pragma unroll
        for (int s = 0; s < 2; ++s) {
            #pragma unroll
            for (int r = 0; r < 16; ++r) {
                int o = (wid*2 + s)*32 + (r & 3) + 8*(r >> 2) + 4*h;
                dst[(size_t)o * Nn + n0 + l31] = f2bf(acc[s][r] + bv[o]);
            }
        }
    }
}

// ---------------------------------------------------------------- attn
// grid 512, block 256 (4 waves). Block = one 32-query tile; wave w handles
// keys [w*1024, (w+1)*1024). NO barriers in main loop. End: LDS combine.
__global__ __launch_bounds__(256, 2) void attn_kernel(
    const short* __restrict__ QTg, const short* __restrict__ KTg,
    const short* __restrict__ Vg, short* __restrict__ ATT)
{
    const int bid = blockIdx.x;
    const int b  = (bid & 7) >> 1;               // batch per XCD pair
    const int qt = ((bid >> 3) << 1) | (bid & 1);
    const int i0 = qt * 32;

    const int t = threadIdx.x, lane = t & 63, wid = t >> 6, h = lane >> 5, l31 = lane & 31;

    __shared__ float Osum[4][32][67];            // fp32 partials (pad 67: conflict-free)
    __shared__ alignas(16) short Obf[4][32][72]; // bf16 [i][c] chunks
    __shared__ float lred[4][32];

    const short* Qb = QTg + (size_t)b * Nn * Cc;
    const short* Kb = KTg + (size_t)b * Nn * Cc;
    const short* Vb = Vg  + (size_t)b * Cc * Nn;

    const float SC = 0.09016844005f;             // C^-0.5 * log2(e)

    // Q fragments register-resident (B operand: B[k=c][n=i])
    s16x8 qf[16];
    {
        const short* qrow = Qb + (size_t)(i0 + l31) * Cc + h*8;
        #pragma unroll
        for (int kc = 0; kc < 16; ++kc) qf[kc] = *(const s16x8*)(qrow + kc*16);
    }

    f32x16 oacc[8];                              // O^T: 256c x 32i
    #pragma unroll
    for (int s = 0; s < 8; ++s)
        #pragma unroll
        for (int r = 0; r < 16; ++r) oacc[s][r] = 0.f;
    float lacc = 0.f;

    for (int jt = wid*16; jt < wid*16 + 16; ++jt) {
        const int j0 = jt * 64;
        #pragma unroll
        for (int sub = 0; sub < 2; ++sub) {
            const int jb = j0 + sub*32;
            // S^T[j][i] = sum_c K^T[j][c] Q[c][i]
            const short* krow = Kb + (size_t)(jb + l31) * Cc + h*8;
            f32x16 s;
            #pragma unroll
            for (int r = 0; r < 16; ++r) s[r] = 0.f;
            #pragma unroll
            for (int kc = 0; kc < 16; ++kc)
                s = MFMA32(*(const s16x8*)(krow + kc*16), qf[kc], s);

            // exp + pack (no-max softmax: |logit| <~ 6)
            unsigned int P[8];
            #pragma unroll
            for (int g = 0; g < 8; ++g) {
                float e0 = exp2f(s[2*g+0] * SC);
                float e1 = exp2f(s[2*g+1] * SC);
                lacc += e0 + e1;
                P[g] = pk2(e0, e1);
            }
            // in-register C->B layout transform: 8 packed half-wave swaps
            unsigned int X[8];
            #pragma unroll
            for (int g = 0; g < 8; ++g)
                X[g] = (unsigned int)__shfl_xor((int)P[g], 32);
            u32x4 w1 = h ? u32x4{X[2], X[3], P[2], P[3]} : u32x4{P[0], P[1], X[0], X[1]};
            u32x4 w2 = h ? u32x4{X[6], X[7], P[6], P[7]} : u32x4{P[4], P[5], X[4], X[5]};
            s16x8 pf1 = __builtin_bit_cast(s16x8, w1);   // k = j 0..15
            s16x8 pf2 = __builtin_bit_cast(s16x8, w2);   // k = j 16..31

            // O^T[c][i] += V[c][j] P^T[j][i]
            #pragma unroll
            for (int ct = 0; ct < 8; ++ct) {
                const short* vr = Vb + (size_t)(ct*32 + l31) * Nn + jb + h*8;
                oacc[ct] = MFMA32(*(const s16x8*)vr,        pf1, oacc[ct]);
                oacc[ct] = MFMA32(*(const s16x8*)(vr + 16), pf2, oacc[ct]);
            }
        }
    }

    // ---------------- combine across the 4 j-split waves
    lacc += __shfl_xor(lacc, 32);
    if (h == 0) lred[wid][l31] = lacc;

    // phase 0: each wave writes its own c-chunk (tiles 2w, 2w+1)
    #pragma unroll
    for (int half = 0; half < 2; ++half)
        #pragma unroll
        for (int r = 0; r < 16; ++r)
            Osum[wid][l31][half*32 + (r & 3) + 8*(r >> 2) + 4*h] = oacc[wid*2 + half][r];
    __syncthreads();

    const float linv = 1.0f / (lred[0][l31] + lred[1][l31] + lred[2][l31] + lred[3][l31]);

    // rounds 1,2: rotate chunks, read-add-write (one owner per chunk per round)
    #pragma unroll
    for (int rho = 1; rho <= 2; ++rho) {
        const int cx = (wid + rho) & 3;
        #pragma unroll
        for (int half = 0; half < 2; ++half)
            #pragma unroll
            for (int r = 0; r < 16; ++r) {
                const int cl = half*32 + (r & 3) + 8*(r >> 2) + 4*h;
                Osum[cx][l31][cl] += oacc[cx*2 + half][r];
            }
        __syncthreads();
    }
    // round 3: final add in regs, normalize, cvt to bf16 [i][c] tile
    {
        const int cx = (wid + 3) & 3;
        #pragma unroll
        for (int half = 0; half < 2; ++half)
            #pragma unroll
            for (int r = 0; r < 16; ++r) {
                const int cl = half*32 + (r & 3) + 8*(r >> 2) + 4*h;
                float v = Osum[cx][l31][cl] + oacc[cx*2 + half][r];
                Obf[cx][l31][cl] = f2bf(v * linv);
            }
    }
    __syncthreads();

    // coalesced store of chunk (wid+3)&3 to ATT [n][c]
    {
        const int cx = (wid + 3) & 3;
        short* Ab = ATT + (size_t)b * Nn * Cc;
        #pragma unroll
        for (int it = 0; it < 4; ++it) {
            int row = it*8 + (lane >> 3), c16 = (lane & 7) * 8;
            *(s16x8*)&Ab[(size_t)(i0 + row) * Cc + cx*64 + c16] =
                *(const s16x8*)&Obf[cx][row][c16];
        }
    }
}

// ---------------------------------------------------------------- proj
__global__ __launch_bounds__(256, 4) void proj_kernel(
    const short* __restrict__ ATT, const short* __restrict__ W,
    const float* __restrict__ bp, const float* __restrict__ x,
    float* __restrict__ out)
{
    const int nt = blockIdx.x, b = blockIdx.y, oh = blockIdx.z;
    const int n0 = nt * 64;
    const int t = threadIdx.x, lane = t & 63, wid = t >> 6, h = lane >> 5, l31 = lane & 31;
    const short* A = ATT + (size_t)b * Nn * Cc;
    const short* Wp = W + 3 * 65536;

    f32x16 acc[2];
    #pragma unroll
    for (int s = 0; s < 2; ++s)
        #pragma unroll
        for (int r = 0; r < 16; ++r) acc[s][r] = 0.f;

    const int og = oh*128 + wid*32;
    #pragma unroll 4
    for (int kk = 0; kk < 16; ++kk) {
        s16x8 a  = *(const s16x8*)&Wp[(size_t)(og + l31) * Cc + kk*16 + h*8];
        s16x8 b0 = *(const s16x8*)&A[(size_t)(n0 +  0 + l31) * Cc + kk*16 + h*8];
        s16x8 b1 = *(const s16x8*)&A[(size_t)(n0 + 32 + l31) * Cc + kk*16 + h*8];
        acc[0] = MFMA32(a, b0, acc[0]);
        acc[1] = MFMA32(a, b1, acc[1]);
    }

    const float* xb = x + (size_t)b * Cc * Nn;
    float* ob = out + (size_t)b * Cc * Nn;
    #pragma unroll
    for (int nc = 0; nc < 2; ++nc) {
        int nloc = nc*32 + l31;
        #pragma unroll
        for (int r = 0; r < 16; ++r) {
            int o = og + (r & 3) + 8*(r >> 2) + 4*h;
            size_t idx = (size_t)o * Nn + n0 + nloc;
            ob[idx] = xb[idx] + acc[nc][r] + bp[o];
        }
    }
}

// ---------------------------------------------------------------- launch
extern "C" void kernel_launch(void* const* d_in, const int* in_sizes, int n_in,
                              void* d_out, int out_size, void* d_ws, size_t ws_size,
                              hipStream_t stream)
{
    const float* x  = (const float*)d_in[0];
    const float* wq = (const float*)d_in[1];
    const float* bq = (const float*)d_in[2];
    const float* wk = (const float*)d_in[3];
    const float* bk = (const float*)d_in[4];
    const float* wv = (const float*)d_in[5];
    const float* bv = (const float*)d_in[6];
    const float* wp = (const float*)d_in[7];
    const float* bp = (const float*)d_in[8];

    const size_t elems = (size_t)4 * Nn * Cc;                 // 4.19 M / buffer
    const size_t need  = (3 * elems + 4 * 65536) * sizeof(short);  // 25.7 MiB
    if (ws_size < need) return;
    short* QT  = (short*)d_ws;                 // [b][n][c] bf16  (= ATT out)
    short* KT  = QT + elems;                   // [b][n][c] bf16
    short* V   = KT + elems;                   // [b][c][n] bf16
    short* Wbf = V + elems;                    // 4 x [o][c] bf16
    short* ATT = QT;                           // block-local self-overwrite
    (void)in_sizes; (void)n_in; (void)out_size;

    wcvt_kernel<<<dim3(32, 4), 256, 0, stream>>>(wq, wk, wv, wp, Wbf);
    qkv_kernel<<<dim3(128, 4), 256, 0, stream>>>(x, Wbf, bq, bk, bv, QT, KT, V);
    attn_kernel<<<dim3(512), 256, 0, stream>>>(QT, KT, V, ATT);
    proj_kernel<<<dim3(64, 4, 2), 256, 0, stream>>>(ATT, Wbf, bp, x, (float*)d_out);
}

// Round 7
// 287.500 us; speedup vs baseline: 1.4607x; 1.4607x over previous
//
#include <hip/hip_runtime.h>
#include <hip/hip_bf16.h>

// NonLocalBlock B=4,C=256,H=W=64 (N=4096) — round 7.
//  wcvt : weights fp32 -> bf16 once
//  qkv  : 32-token tiles, grid 512 (2 blocks/CU), LDS x-transpose + MFMA
//  attn : 64q blocks, 8 waves. Per 256-key chunk: wave w computes S for its
//         32-j strip (K,Q from L2/regs), exp -> P into dbuf LDS tile; then
//         consumes full 256-j P against its 32-c V strip (V from L2).
//         ONE barrier per 256 keys. proj+residual FUSED in epilogue.
// ws = QT | KT | V | Wbf = 24.5 MiB.

typedef __attribute__((ext_vector_type(4))) short s16x4;
typedef __attribute__((ext_vector_type(8))) short s16x8;
typedef __attribute__((ext_vector_type(16))) float f32x16;

#define MFMA32(a, b, c) __builtin_amdgcn_mfma_f32_32x32x16_bf16((a), (b), (c), 0, 0, 0)

constexpr int Cc = 256;
constexpr int Nn = 4096;

__device__ inline short f2bf(float f) {
    unsigned int u = __builtin_bit_cast(unsigned int, f);
    u = (u + 0x7fffu + ((u >> 16) & 1u)) >> 16;   // RNE
    return (short)u;
}

// 32x32x16 bf16 MFMA layouts (m74/m101-verified C/D; A/B symmetric k-map):
//   A[m=lane&31][k=(lane>>5)*8+j]   B[k=(lane>>5)*8+j][n=lane&31]
//   C/D: col=lane&31, row=(r&3)+8*(r>>2)+4*(lane>>5)

// ---------------------------------------------------------------- wcvt
__global__ __launch_bounds__(256, 4) void wcvt_kernel(
    const float* __restrict__ wq, const float* __restrict__ wk,
    const float* __restrict__ wv, const float* __restrict__ wp,
    short* __restrict__ W)
{
    const int m = blockIdx.y;
    const float* src = (m == 0) ? wq : (m == 1) ? wk : (m == 2) ? wv : wp;
    const int idx = (blockIdx.x * 256 + threadIdx.x) * 8;
    float4 a = *(const float4*)(src + idx);
    float4 b = *(const float4*)(src + idx + 4);
    s16x8 p = { f2bf(a.x), f2bf(a.y), f2bf(a.z), f2bf(a.w),
                f2bf(b.x), f2bf(b.y), f2bf(b.z), f2bf(b.w) };
    *(s16x8*)(W + m * 65536 + idx) = p;
}

// ---------------------------------------------------------------- qkv
// 32-token tiles, grid (128 nt, 4 b) = 512 blocks -> 2 blocks/CU.
__global__ __launch_bounds__(256, 2) void qkv_kernel(
    const float* __restrict__ x, const short* __restrict__ W,
    const float* __restrict__ bq, const float* __restrict__ bk,
    const float* __restrict__ bv,
    short* __restrict__ QT, short* __restrict__ KT, short* __restrict__ V)
{
    const int nt = blockIdx.x, b = blockIdx.y;
    const int n0 = nt * 32;
    const int t = threadIdx.x, lane = t & 63, wid = t >> 6, h = lane >> 5, l31 = lane & 31;

    __shared__ alignas(16) short xT[32][264];      // x^T tile [n][c] bf16

    const float* xb = x + (size_t)b * Cc * Nn;
    #pragma unroll
    for (int r = 0; r < 8; ++r) {                  // 32n x 256c transpose+cvt
        int idx = r * 256 + t;
        int n = idx & 31, c = (idx >> 5) * 4;
        float f0 = xb[(size_t)(c + 0) * Nn + n0 + n];
        float f1 = xb[(size_t)(c + 1) * Nn + n0 + n];
        float f2 = xb[(size_t)(c + 2) * Nn + n0 + n];
        float f3 = xb[(size_t)(c + 3) * Nn + n0 + n];
        s16x4 p = { f2bf(f0), f2bf(f1), f2bf(f2), f2bf(f3) };
        *(s16x4*)&xT[n][c] = p;
    }
    __syncthreads();

    // ---- Q,K: D[n][o] (A = xT rows, B = W rows)
    #pragma unroll
    for (int mat = 0; mat < 2; ++mat) {
        const short* Wm = W + mat * 65536;
        const float* bias = (mat == 0) ? bq : bk;
        f32x16 acc[2];
        #pragma unroll
        for (int s = 0; s < 2; ++s)
            #pragma unroll
            for (int r = 0; r < 16; ++r) acc[s][r] = 0.f;
        #pragma unroll 4
        for (int kk = 0; kk < 16; ++kk) {
            s16x8 a = *(const s16x8*)&xT[l31][kk*16 + h*8];
            #pragma unroll
            for (int s = 0; s < 2; ++s) {
                int ot = wid*2 + s;
                s16x8 bb = *(const s16x8*)&Wm[(size_t)(ot*32 + l31) * Cc + kk*16 + h*8];
                acc[s] = MFMA32(a, bb, acc[s]);
            }
        }
        short* dst = ((mat == 0) ? QT : KT) + (size_t)b * Nn * Cc;
        #pragma unroll
        for (int s = 0; s < 2; ++s) {
            int o = (wid*2 + s)*32 + l31;
            float bia = bias[o];
            #pragma unroll
            for (int r = 0; r < 16; ++r) {
                int n = (r & 3) + 8*(r >> 2) + 4*h;
                dst[(size_t)(n0 + n) * Cc + o] = f2bf(acc[s][r] + bia);
            }
        }
    }

    // ---- V: D[o][n] (A = W rows, B = xT rows)
    {
        const short* Wm = W + 2 * 65536;
        f32x16 acc[2];
        #pragma unroll
        for (int s = 0; s < 2; ++s)
            #pragma unroll
            for (int r = 0; r < 16; ++r) acc[s][r] = 0.f;
        #pragma unroll 4
        for (int kk = 0; kk < 16; ++kk) {
            s16x8 bx = *(const s16x8*)&xT[l31][kk*16 + h*8];
            #pragma unroll
            for (int s = 0; s < 2; ++s) {
                int ot = wid*2 + s;
                s16x8 aw = *(const s16x8*)&Wm[(size_t)(ot*32 + l31) * Cc + kk*16 + h*8];
                acc[s] = MFMA32(aw, bx, acc[s]);
            }
        }
        short* dst = V + (size_t)b * Cc * Nn;
        #pragma unroll
        for (int s = 0; s < 2; ++s) {
            #pragma unroll
            for (int r = 0; r < 16; ++r) {
                int o = (wid*2 + s)*32 + (r & 3) + 8*(r >> 2) + 4*h;
                dst[(size_t)o * Nn + n0 + l31] = f2bf(acc[s][r] + bv[o]);
            }
        }
    }
}

// ---------------------------------------------------------------- attn (+proj)
// grid 256, block 512 (8 waves). Block = 64-query tile.
// LDS: Ps[2][64][264] 67.6 KB + lred 2 KB.
__global__ __launch_bounds__(512, 1) void attn_kernel(
    const short* __restrict__ QTg, const short* __restrict__ KTg,
    const short* __restrict__ Vg, const short* __restrict__ W,
    const float* __restrict__ bp, const float* __restrict__ x,
    float* __restrict__ out)
{
    const int bid = blockIdx.x;
    const int b  = (bid & 7) >> 1;               // batch per XCD pair
    const int qt = ((bid >> 3) << 1) | (bid & 1);
    const int i0 = qt * 64;

    const int t = threadIdx.x, lane = t & 63, wid = t >> 6, h = lane >> 5, l31 = lane & 31;
    const int jw = wid * 32;                     // wave's j-strip in chunk
    const int cw = wid * 32;                     // wave's c-strip for PV/proj

    __shared__ alignas(16) short Ps[2][64][264];
    __shared__ float lred[8][2][32];

    const short* Qb = QTg + (size_t)b * Nn * Cc;
    const short* Kb = KTg + (size_t)b * Nn * Cc;
    const short* Vb = Vg  + (size_t)b * Cc * Nn;

    const float SC = 0.09016844005f;             // C^-0.5 * log2(e)

    // Q fragments register-resident (B operand: B[k=c][n=i]), 2 i-tiles
    s16x8 qf[2][16];
    #pragma unroll
    for (int it = 0; it < 2; ++it) {
        const short* qrow = Qb + (size_t)(i0 + it*32 + l31) * Cc + h*8;
        #pragma unroll
        for (int kc = 0; kc < 16; ++kc) qf[it][kc] = *(const s16x8*)(qrow + kc*16);
    }

    f32x16 oacc[2];
    #pragma unroll
    for (int it = 0; it < 2; ++it)
        #pragma unroll
        for (int r = 0; r < 16; ++r) oacc[it][r] = 0.f;
    float lacc0 = 0.f, lacc1 = 0.f;

    // ---- produce chunk 0
    {
        s16x8 kf[16];
        const short* krow = Kb + (size_t)(0 + jw + l31) * Cc + h*8;
        #pragma unroll
        for (int kc = 0; kc < 16; ++kc) kf[kc] = *(const s16x8*)(krow + kc*16);
        f32x16 s0, s1;
        #pragma unroll
        for (int r = 0; r < 16; ++r) { s0[r] = 0.f; s1[r] = 0.f; }
        #pragma unroll
        for (int kc = 0; kc < 16; ++kc) {
            s0 = MFMA32(kf[kc], qf[0][kc], s0);
            s1 = MFMA32(kf[kc], qf[1][kc], s1);
        }
        #pragma unroll
        for (int it = 0; it < 2; ++it) {
            const int ip = it*32 + l31;
            #pragma unroll
            for (int g = 0; g < 4; ++g) {
                float e0 = exp2f((it ? s1[4*g+0] : s0[4*g+0]) * SC);
                float e1 = exp2f((it ? s1[4*g+1] : s0[4*g+1]) * SC);
                float e2 = exp2f((it ? s1[4*g+2] : s0[4*g+2]) * SC);
                float e3 = exp2f((it ? s1[4*g+3] : s0[4*g+3]) * SC);
                if (it) lacc1 += e0+e1+e2+e3; else lacc0 += e0+e1+e2+e3;
                s16x4 pk = { f2bf(e0), f2bf(e1), f2bf(e2), f2bf(e3) };
                *(s16x4*)&Ps[0][ip][jw + g*8 + 4*h] = pk;
            }
        }
    }
    __syncthreads();

    // ---- main loop: PV chunk n-1 + QK chunk n
    for (int n = 1; n < 16; ++n) {
        const int jc0 = n * 256, jp0 = jc0 - 256;
        const int pb = (n - 1) & 1, cb = n & 1;

        s16x8 vf[16];
        {
            const short* vrow = Vb + (size_t)(cw + l31) * Nn + jp0 + h*8;
            #pragma unroll
            for (int ks = 0; ks < 16; ++ks) vf[ks] = *(const s16x8*)(vrow + ks*16);
        }
        s16x8 kf[16];
        {
            const short* krow = Kb + (size_t)(jc0 + jw + l31) * Cc + h*8;
            #pragma unroll
            for (int kc = 0; kc < 16; ++kc) kf[kc] = *(const s16x8*)(krow + kc*16);
        }

        // PV: O^T[c][i] += V[c][j] P^T[j][i]
        #pragma unroll
        for (int ks = 0; ks < 16; ++ks) {
            s16x8 p0 = *(const s16x8*)&Ps[pb][ 0 + l31][ks*16 + h*8];
            s16x8 p1 = *(const s16x8*)&Ps[pb][32 + l31][ks*16 + h*8];
            oacc[0] = MFMA32(vf[ks], p0, oacc[0]);
            oacc[1] = MFMA32(vf[ks], p1, oacc[1]);
        }

        // QK: S^T[j][i] for wave's 32-j strip
        f32x16 s0, s1;
        #pragma unroll
        for (int r = 0; r < 16; ++r) { s0[r] = 0.f; s1[r] = 0.f; }
        #pragma unroll
        for (int kc = 0; kc < 16; ++kc) {
            s0 = MFMA32(kf[kc], qf[0][kc], s0);
            s1 = MFMA32(kf[kc], qf[1][kc], s1);
        }
        #pragma unroll
        for (int it = 0; it < 2; ++it) {
            const int ip = it*32 + l31;
            #pragma unroll
            for (int g = 0; g < 4; ++g) {
                float e0 = exp2f((it ? s1[4*g+0] : s0[4*g+0]) * SC);
                float e1 = exp2f((it ? s1[4*g+1] : s0[4*g+1]) * SC);
                float e2 = exp2f((it ? s1[4*g+2] : s0[4*g+2]) * SC);
                float e3 = exp2f((it ? s1[4*g+3] : s0[4*g+3]) * SC);
                if (it) lacc1 += e0+e1+e2+e3; else lacc0 += e0+e1+e2+e3;
                s16x4 pk = { f2bf(e0), f2bf(e1), f2bf(e2), f2bf(e3) };
                *(s16x4*)&Ps[cb][ip][jw + g*8 + 4*h] = pk;
            }
        }
        __syncthreads();
    }

    // ---- final PV (chunk 15, buffer 1)
    {
        const int jp0 = 15 * 256;
        s16x8 vf[16];
        const short* vrow = Vb + (size_t)(cw + l31) * Nn + jp0 + h*8;
        #pragma unroll
        for (int ks = 0; ks < 16; ++ks) vf[ks] = *(const s16x8*)(vrow + ks*16);
        #pragma unroll
        for (int ks = 0; ks < 16; ++ks) {
            s16x8 p0 = *(const s16x8*)&Ps[1][ 0 + l31][ks*16 + h*8];
            s16x8 p1 = *(const s16x8*)&Ps[1][32 + l31][ks*16 + h*8];
            oacc[0] = MFMA32(vf[ks], p0, oacc[0]);
            oacc[1] = MFMA32(vf[ks], p1, oacc[1]);
        }
    }

    // ---- softmax denominators (sum over the 8 wave j-strips)
    lacc0 += __shfl_xor(lacc0, 32);
    lacc1 += __shfl_xor(lacc1, 32);
    if (h == 0) { lred[wid][0][l31] = lacc0; lred[wid][1][l31] = lacc1; }
    __syncthreads();
    float linv[2];
    #pragma unroll
    for (int it = 0; it < 2; ++it) {
        float sum = 0.f;
        #pragma unroll
        for (int w = 0; w < 8; ++w) sum += lred[w][it][l31];
        linv[it] = 1.0f / sum;
    }

    // ---- normalize into LDS O tile [i][c] (over Ps[0])
    short (*T)[264] = Ps[0];
    #pragma unroll
    for (int it = 0; it < 2; ++it) {
        const int ip = it*32 + l31;
        #pragma unroll
        for (int r = 0; r < 16; ++r) {
            int c = cw + (r & 3) + 8*(r >> 2) + 4*h;
            T[ip][c] = f2bf(oacc[it][r] * linv[it]);
        }
    }
    __syncthreads();

    // ---- fused projection + residual: out = x + Wp·O + bp
    const short* Wp = W + 3 * 65536;
    f32x16 pacc[2];
    #pragma unroll
    for (int it = 0; it < 2; ++it)
        #pragma unroll
        for (int r = 0; r < 16; ++r) pacc[it][r] = 0.f;
    #pragma unroll 4
    for (int kc = 0; kc < 16; ++kc) {
        s16x8 wa = *(const s16x8*)&Wp[(size_t)(cw + l31) * Cc + kc*16 + h*8];
        s16x8 b0 = *(const s16x8*)&T[ 0 + l31][kc*16 + h*8];
        s16x8 b1 = *(const s16x8*)&T[32 + l31][kc*16 + h*8];
        pacc[0] = MFMA32(wa, b0, pacc[0]);
        pacc[1] = MFMA32(wa, b1, pacc[1]);
    }
    const float* xb = x + (size_t)b * Cc * Nn;
    float* ob = out + (size_t)b * Cc * Nn;
    #pragma unroll
    for (int it = 0; it < 2; ++it) {
        int iloc = i0 + it*32 + l31;
        #pragma unroll
        for (int r = 0; r < 16; ++r) {
            int o = cw + (r & 3) + 8*(r >> 2) + 4*h;
            size_t idx = (size_t)o * Nn + iloc;
            ob[idx] = xb[idx] + pacc[it][r] + bp[o];
        }
    }
}

// ---------------------------------------------------------------- launch
extern "C" void kernel_launch(void* const* d_in, const int* in_sizes, int n_in,
                              void* d_out, int out_size, void* d_ws, size_t ws_size,
                              hipStream_t stream)
{
    const float* x  = (const float*)d_in[0];
    const float* wq = (const float*)d_in[1];
    const float* bq = (const float*)d_in[2];
    const float* wk = (const float*)d_in[3];
    const float* bk = (const float*)d_in[4];
    const float* wv = (const float*)d_in[5];
    const float* bv = (const float*)d_in[6];
    const float* wp = (const float*)d_in[7];
    const float* bp = (const float*)d_in[8];

    const size_t elems = (size_t)4 * Nn * Cc;                 // 4.19 M / buffer
    const size_t need  = (3 * elems + 4 * 65536) * sizeof(short);  // 24.5 MiB
    if (ws_size < need) return;
    short* QT  = (short*)d_ws;                 // [b][n][c] bf16
    short* KT  = QT + elems;                   // [b][n][c] bf16
    short* V   = KT + elems;                   // [b][c][n] bf16
    short* Wbf = V + elems;                    // 4 x [o][c] bf16
    (void)in_sizes; (void)n_in; (void)out_size;

    wcvt_kernel<<<dim3(32, 4), 256, 0, stream>>>(wq, wk, wv, wp, Wbf);
    qkv_kernel<<<dim3(128, 4), 256, 0, stream>>>(x, Wbf, bq, bk, bv, QT, KT, V);
    attn_kernel<<<dim3(256), 512, 0, stream>>>(QT, KT, V, Wbf, bp, x, (float*)d_out);
}